// Round 1
// baseline (5557.713 us; speedup 1.0000x reference)
//
#include <hip/hip_runtime.h>

// Problem constants (from reference)
#define NN 100000
#define EE 1600000
#define DD 128   // input dim
#define HH 128   // hidden dim
#define OO 64    // output dim

// ---------------------------------------------------------------------------
// ew = sigmoid(edge_weight)
__global__ void sigmoid_k(const float* __restrict__ w, float* __restrict__ ew, int E) {
  int i = blockIdx.x * blockDim.x + threadIdx.x;
  if (i < E) ew[i] = 1.0f / (1.0f + expf(-w[i]));
}

// ---------------------------------------------------------------------------
// Scatter-add: aggr[dst] += feat[src] * ew[e].  32 threads per edge, float4 each.
__global__ __launch_bounds__(256) void scatter_k(
    const float* __restrict__ feat, const int* __restrict__ ei,
    const float* __restrict__ ew, float* __restrict__ aggr, int E) {
  long long gid = (long long)blockIdx.x * 256 + threadIdx.x;
  long long e = gid >> 5;           // edge id
  int c = (int)(gid & 31);          // float4 chunk within 128 features
  if (e >= E) return;
  int src = ei[e];
  int dst = ei[E + e];
  float w = ew[e];
  float4 v = *reinterpret_cast<const float4*>(feat + (size_t)src * DD + c * 4);
  float* o = aggr + (size_t)dst * DD + c * 4;
  atomicAdd(o + 0, v.x * w);
  atomicAdd(o + 1, v.y * w);
  atomicAdd(o + 2, v.z * w);
  atomicAdd(o + 3, v.w * w);
}

// ---------------------------------------------------------------------------
// Fused dual-GEMM epilogue:  C = (relu?)( A1@W1 + A2@W2 + bias )
// A1,A2: [n_rows, 128] row-major.  W1,W2: [128, HO] row-major.  C: [n_rows, HO].
template <int HO, bool RELU>
__global__ __launch_bounds__(256) void gemm_fused_k(
    const float* __restrict__ A1, const float* __restrict__ A2,
    const float* __restrict__ W1, const float* __restrict__ W2,
    const float* __restrict__ bias, float* __restrict__ C, int n_rows) {
  constexpr int BN = 64;    // nodes per tile
  constexpr int K = 128;
  constexpr int BK = 32;
  constexpr int OG = HO / 4;    // output groups (one float4 each)
  constexpr int NG = 256 / OG;  // node groups
  constexpr int NPG = BN / NG;  // nodes per thread

  __shared__ float A1s[BN][BK];
  __shared__ float A2s[BN][BK];
  __shared__ float W1s[BK][HO];
  __shared__ float W2s[BK][HO];

  const int t = threadIdx.x;
  const int og = t % OG;
  const int ng = t / OG;
  const int row0 = blockIdx.x * BN;

  float4 acc[NPG];
#pragma unroll
  for (int i = 0; i < NPG; ++i) acc[i] = make_float4(0.f, 0.f, 0.f, 0.f);

  for (int k0 = 0; k0 < K; k0 += BK) {
    // Stage A tiles (BN x BK), float4 granules
#pragma unroll
    for (int i = t; i < BN * BK / 4; i += 256) {
      int n = i / (BK / 4);
      int kq = i % (BK / 4);
      int gr = row0 + n;
      float4 a1 = make_float4(0.f, 0.f, 0.f, 0.f);
      float4 a2 = make_float4(0.f, 0.f, 0.f, 0.f);
      if (gr < n_rows) {
        a1 = *reinterpret_cast<const float4*>(&A1[(size_t)gr * K + k0 + kq * 4]);
        a2 = *reinterpret_cast<const float4*>(&A2[(size_t)gr * K + k0 + kq * 4]);
      }
      *reinterpret_cast<float4*>(&A1s[n][kq * 4]) = a1;
      *reinterpret_cast<float4*>(&A2s[n][kq * 4]) = a2;
    }
    // Stage W tiles (BK x HO)
#pragma unroll
    for (int i = t; i < BK * HO / 4; i += 256) {
      int kk = i / (HO / 4);
      int hq = i % (HO / 4);
      *reinterpret_cast<float4*>(&W1s[kk][hq * 4]) =
          *reinterpret_cast<const float4*>(&W1[(size_t)(k0 + kk) * HO + hq * 4]);
      *reinterpret_cast<float4*>(&W2s[kk][hq * 4]) =
          *reinterpret_cast<const float4*>(&W2[(size_t)(k0 + kk) * HO + hq * 4]);
    }
    __syncthreads();

#pragma unroll
    for (int kk = 0; kk < BK; ++kk) {
      float4 w1 = *reinterpret_cast<const float4*>(&W1s[kk][og * 4]);
      float4 w2 = *reinterpret_cast<const float4*>(&W2s[kk][og * 4]);
#pragma unroll
      for (int i = 0; i < NPG; ++i) {
        float a1 = A1s[ng * NPG + i][kk];
        float a2 = A2s[ng * NPG + i][kk];
        acc[i].x = fmaf(a1, w1.x, acc[i].x);
        acc[i].y = fmaf(a1, w1.y, acc[i].y);
        acc[i].z = fmaf(a1, w1.z, acc[i].z);
        acc[i].w = fmaf(a1, w1.w, acc[i].w);
        acc[i].x = fmaf(a2, w2.x, acc[i].x);
        acc[i].y = fmaf(a2, w2.y, acc[i].y);
        acc[i].z = fmaf(a2, w2.z, acc[i].z);
        acc[i].w = fmaf(a2, w2.w, acc[i].w);
      }
    }
    __syncthreads();
  }

  const float4 b4 = *reinterpret_cast<const float4*>(&bias[og * 4]);
#pragma unroll
  for (int i = 0; i < NPG; ++i) {
    int gr = row0 + ng * NPG + i;
    if (gr < n_rows) {
      float4 o;
      o.x = acc[i].x + b4.x;
      o.y = acc[i].y + b4.y;
      o.z = acc[i].z + b4.z;
      o.w = acc[i].w + b4.w;
      if (RELU) {
        o.x = fmaxf(o.x, 0.f);
        o.y = fmaxf(o.y, 0.f);
        o.z = fmaxf(o.z, 0.f);
        o.w = fmaxf(o.w, 0.f);
      }
      *reinterpret_cast<float4*>(&C[(size_t)gr * HO + og * 4]) = o;
    }
  }
}

// ---------------------------------------------------------------------------
extern "C" void kernel_launch(void* const* d_in, const int* in_sizes, int n_in,
                              void* d_out, int out_size, void* d_ws, size_t ws_size,
                              hipStream_t stream) {
  const float* x   = (const float*)d_in[0];
  const float* w   = (const float*)d_in[1];
  const int*   ei  = (const int*)d_in[2];   // [2, E]: row0=src, row1=dst
  const float* Wr1 = (const float*)d_in[3];
  const float* br1 = (const float*)d_in[4];
  const float* Wo1 = (const float*)d_in[5];
  const float* Wr2 = (const float*)d_in[6];
  const float* br2 = (const float*)d_in[7];
  const float* Wo2 = (const float*)d_in[8];
  float* out = (float*)d_out;

  char* ws = (char*)d_ws;
  float* ew   = (float*)(ws);                              // E floats      (6.4 MB)
  float* aggr = (float*)(ws + 6400000);                    // N*128 floats  (51.2 MB)
  float* h    = (float*)(ws + 6400000 + 51200000);         // N*128 floats  (51.2 MB)

  // ew = sigmoid(edge_weight)
  sigmoid_k<<<(EE + 255) / 256, 256, 0, stream>>>(w, ew, EE);

  // ---- Layer 1 ----
  hipMemsetAsync(aggr, 0, (size_t)NN * DD * sizeof(float), stream);
  scatter_k<<<(EE * 32) / 256, 256, 0, stream>>>(x, ei, ew, aggr, EE);
  gemm_fused_k<HH, true><<<(NN + 63) / 64, 256, 0, stream>>>(aggr, x, Wr1, Wo1, br1, h, NN);

  // ---- Layer 2 ----
  hipMemsetAsync(aggr, 0, (size_t)NN * DD * sizeof(float), stream);
  scatter_k<<<(EE * 32) / 256, 256, 0, stream>>>(h, ei, ew, aggr, EE);
  gemm_fused_k<OO, false><<<(NN + 63) / 64, 256, 0, stream>>>(aggr, h, Wr2, Wo2, br2, out, NN);
}

// Round 2
// 823.269 us; speedup vs baseline: 6.7508x; 6.7508x over previous
//
#include <hip/hip_runtime.h>

// Problem constants (from reference)
#define NN 100000
#define EE 1600000
#define DD 128   // input dim
#define HH 128   // hidden dim
#define OO 64    // output dim

// ---------------------------------------------------------------------------
// Pass 1: count in-degree per destination node (into cursor[])
__global__ __launch_bounds__(256) void count_k(const int* __restrict__ ei,
                                               int* __restrict__ cnt, int E) {
  int e = blockIdx.x * 256 + threadIdx.x;
  if (e < E) atomicAdd(&cnt[ei[E + e]], 1);
}

// ---------------------------------------------------------------------------
// Pass 2: single-block exclusive scan of counts.
//   in/out: cursor[] holds counts on entry, exclusive prefix on exit.
//   row_off[] gets the same exclusive prefix (stable copy; cursor mutates in fill).
__global__ __launch_bounds__(1024) void scan_k(int* __restrict__ cursor,
                                               int* __restrict__ row_off, int n) {
  __shared__ int sums[1024];
  const int t = threadIdx.x;
  const int chunk = (n + 1023) / 1024;
  const int beg = t * chunk;
  const int end = min(n, beg + chunk);

  int local = 0;
  for (int i = beg; i < end; ++i) local += cursor[i];
  sums[t] = local;
  __syncthreads();
  // inclusive scan over 1024 thread sums
  for (int off = 1; off < 1024; off <<= 1) {
    int v = (t >= off) ? sums[t - off] : 0;
    __syncthreads();
    sums[t] += v;
    __syncthreads();
  }
  int running = sums[t] - local;  // exclusive base for this thread's chunk
  for (int i = beg; i < end; ++i) {
    int d = cursor[i];
    row_off[i] = running;
    cursor[i] = running;
    running += d;
  }
}

// ---------------------------------------------------------------------------
// Pass 3: fill CSR arrays, fusing sigmoid(edge_weight).
__global__ __launch_bounds__(256) void fill_k(const int* __restrict__ ei,
                                              const float* __restrict__ w,
                                              int* __restrict__ cursor,
                                              int* __restrict__ src_s,
                                              float* __restrict__ ew_s, int E) {
  int e = blockIdx.x * 256 + threadIdx.x;
  if (e >= E) return;
  int dst = ei[E + e];
  int pos = atomicAdd(&cursor[dst], 1);
  src_s[pos] = ei[e];
  ew_s[pos] = 1.0f / (1.0f + expf(-w[e]));
}

// ---------------------------------------------------------------------------
// Aggregation as gather: 32 lanes per destination node, one float4 chunk each.
// row range = [row_off[n], row_end[n])  (row_end == cursor after fill).
__global__ __launch_bounds__(256) void gather_k(
    const float* __restrict__ feat, const int* __restrict__ row_off,
    const int* __restrict__ row_end, const int* __restrict__ src_s,
    const float* __restrict__ ew_s, float* __restrict__ aggr) {
  int gid = blockIdx.x * 256 + threadIdx.x;
  int node = gid >> 5;
  int c = gid & 31;
  if (node >= NN) return;
  int beg = row_off[node];
  int end = row_end[node];
  float4 acc = make_float4(0.f, 0.f, 0.f, 0.f);
  for (int e = beg; e < end; ++e) {
    int s = src_s[e];
    float wgt = ew_s[e];
    float4 v = *reinterpret_cast<const float4*>(feat + (size_t)s * DD + c * 4);
    acc.x = fmaf(v.x, wgt, acc.x);
    acc.y = fmaf(v.y, wgt, acc.y);
    acc.z = fmaf(v.z, wgt, acc.z);
    acc.w = fmaf(v.w, wgt, acc.w);
  }
  *reinterpret_cast<float4*>(aggr + (size_t)node * DD + c * 4) = acc;
}

// ---------------------------------------------------------------------------
// Fused dual-GEMM epilogue:  C = (relu?)( A1@W1 + A2@W2 + bias )
// A1,A2: [n_rows, 128] row-major.  W1,W2: [128, HO] row-major.  C: [n_rows, HO].
template <int HO, bool RELU>
__global__ __launch_bounds__(256) void gemm_fused_k(
    const float* __restrict__ A1, const float* __restrict__ A2,
    const float* __restrict__ W1, const float* __restrict__ W2,
    const float* __restrict__ bias, float* __restrict__ C, int n_rows) {
  constexpr int BN = 64;    // nodes per tile
  constexpr int K = 128;
  constexpr int BK = 32;
  constexpr int OG = HO / 4;    // output groups (one float4 each)
  constexpr int NG = 256 / OG;  // node groups
  constexpr int NPG = BN / NG;  // nodes per thread

  __shared__ float A1s[BN][BK];
  __shared__ float A2s[BN][BK];
  __shared__ float W1s[BK][HO];
  __shared__ float W2s[BK][HO];

  const int t = threadIdx.x;
  const int og = t % OG;
  const int ng = t / OG;
  const int row0 = blockIdx.x * BN;

  float4 acc[NPG];
#pragma unroll
  for (int i = 0; i < NPG; ++i) acc[i] = make_float4(0.f, 0.f, 0.f, 0.f);

  for (int k0 = 0; k0 < K; k0 += BK) {
#pragma unroll
    for (int i = t; i < BN * BK / 4; i += 256) {
      int n = i / (BK / 4);
      int kq = i % (BK / 4);
      int gr = row0 + n;
      float4 a1 = make_float4(0.f, 0.f, 0.f, 0.f);
      float4 a2 = make_float4(0.f, 0.f, 0.f, 0.f);
      if (gr < n_rows) {
        a1 = *reinterpret_cast<const float4*>(&A1[(size_t)gr * K + k0 + kq * 4]);
        a2 = *reinterpret_cast<const float4*>(&A2[(size_t)gr * K + k0 + kq * 4]);
      }
      *reinterpret_cast<float4*>(&A1s[n][kq * 4]) = a1;
      *reinterpret_cast<float4*>(&A2s[n][kq * 4]) = a2;
    }
#pragma unroll
    for (int i = t; i < BK * HO / 4; i += 256) {
      int kk = i / (HO / 4);
      int hq = i % (HO / 4);
      *reinterpret_cast<float4*>(&W1s[kk][hq * 4]) =
          *reinterpret_cast<const float4*>(&W1[(size_t)(k0 + kk) * HO + hq * 4]);
      *reinterpret_cast<float4*>(&W2s[kk][hq * 4]) =
          *reinterpret_cast<const float4*>(&W2[(size_t)(k0 + kk) * HO + hq * 4]);
    }
    __syncthreads();

#pragma unroll
    for (int kk = 0; kk < BK; ++kk) {
      float4 w1 = *reinterpret_cast<const float4*>(&W1s[kk][og * 4]);
      float4 w2 = *reinterpret_cast<const float4*>(&W2s[kk][og * 4]);
#pragma unroll
      for (int i = 0; i < NPG; ++i) {
        float a1 = A1s[ng * NPG + i][kk];
        float a2 = A2s[ng * NPG + i][kk];
        acc[i].x = fmaf(a1, w1.x, acc[i].x);
        acc[i].y = fmaf(a1, w1.y, acc[i].y);
        acc[i].z = fmaf(a1, w1.z, acc[i].z);
        acc[i].w = fmaf(a1, w1.w, acc[i].w);
        acc[i].x = fmaf(a2, w2.x, acc[i].x);
        acc[i].y = fmaf(a2, w2.y, acc[i].y);
        acc[i].z = fmaf(a2, w2.z, acc[i].z);
        acc[i].w = fmaf(a2, w2.w, acc[i].w);
      }
    }
    __syncthreads();
  }

  const float4 b4 = *reinterpret_cast<const float4*>(&bias[og * 4]);
#pragma unroll
  for (int i = 0; i < NPG; ++i) {
    int gr = row0 + ng * NPG + i;
    if (gr < n_rows) {
      float4 o;
      o.x = acc[i].x + b4.x;
      o.y = acc[i].y + b4.y;
      o.z = acc[i].z + b4.z;
      o.w = acc[i].w + b4.w;
      if (RELU) {
        o.x = fmaxf(o.x, 0.f);
        o.y = fmaxf(o.y, 0.f);
        o.z = fmaxf(o.z, 0.f);
        o.w = fmaxf(o.w, 0.f);
      }
      *reinterpret_cast<float4*>(&C[(size_t)gr * HO + og * 4]) = o;
    }
  }
}

// ---------------------------------------------------------------------------
extern "C" void kernel_launch(void* const* d_in, const int* in_sizes, int n_in,
                              void* d_out, int out_size, void* d_ws, size_t ws_size,
                              hipStream_t stream) {
  const float* x   = (const float*)d_in[0];
  const float* w   = (const float*)d_in[1];
  const int*   ei  = (const int*)d_in[2];   // [2, E]: row0=src, row1=dst
  const float* Wr1 = (const float*)d_in[3];
  const float* br1 = (const float*)d_in[4];
  const float* Wo1 = (const float*)d_in[5];
  const float* Wr2 = (const float*)d_in[6];
  const float* br2 = (const float*)d_in[7];
  const float* Wo2 = (const float*)d_in[8];
  float* out = (float*)d_out;

  // Workspace layout (bytes):
  char* ws = (char*)d_ws;
  int*   row_off = (int*)(ws);                       // N ints      (400 KB)
  int*   cursor  = (int*)(ws + 400000);              // N ints      (400 KB)
  int*   src_s   = (int*)(ws + 800000);              // E ints      (6.4 MB)
  float* ew_s    = (float*)(ws + 7200000);           // E floats    (6.4 MB)
  float* aggr    = (float*)(ws + 13600000);          // N*128 f32   (51.2 MB)
  float* h       = (float*)(ws + 64800000);          // N*128 f32   (51.2 MB)
  // total: 116.0 MB

  const int egrid = (EE + 255) / 256;

  // ---- Build CSR (grouped by dst), fused sigmoid ----
  hipMemsetAsync(cursor, 0, (size_t)NN * sizeof(int), stream);
  count_k<<<egrid, 256, 0, stream>>>(ei, cursor, EE);
  scan_k<<<1, 1024, 0, stream>>>(cursor, row_off, NN);
  fill_k<<<egrid, 256, 0, stream>>>(ei, w, cursor, src_s, ew_s, EE);
  // after fill: cursor[n] == row_off[n+1]  (row end)

  const int ggrid = (NN * 32 + 255) / 256;

  // ---- Layer 1 ----
  gather_k<<<ggrid, 256, 0, stream>>>(x, row_off, cursor, src_s, ew_s, aggr);
  gemm_fused_k<HH, true><<<(NN + 63) / 64, 256, 0, stream>>>(aggr, x, Wr1, Wo1, br1, h, NN);

  // ---- Layer 2 ----
  gather_k<<<ggrid, 256, 0, stream>>>(h, row_off, cursor, src_s, ew_s, aggr);
  gemm_fused_k<OO, false><<<(NN + 63) / 64, 256, 0, stream>>>(aggr, h, Wr2, Wo2, br2, out, NN);
}

// Round 3
// 617.842 us; speedup vs baseline: 8.9954x; 1.3325x over previous
//
#include <hip/hip_runtime.h>

// Problem constants (from reference)
#define NN 100000
#define EE 1600000
#define DD 128   // input dim
#define HH 128   // hidden dim
#define OO 64    // output dim

#define SCAN_BLOCKS 256

// ---------------------------------------------------------------------------
// Pass 1: count in-degree per destination node (into cursor[])
__global__ __launch_bounds__(256) void count_k(const int* __restrict__ ei,
                                               int* __restrict__ cnt, int E) {
  int e = blockIdx.x * 256 + threadIdx.x;
  if (e < E) atomicAdd(&cnt[ei[E + e]], 1);
}

// ---------------------------------------------------------------------------
// Pass 2a: per-block partial sums of cnt[] chunks.
__global__ __launch_bounds__(256) void scan_partial_k(const int* __restrict__ cnt,
                                                      int* __restrict__ blk_sum, int n) {
  __shared__ int red[256];
  const int chunk = (n + SCAN_BLOCKS - 1) / SCAN_BLOCKS;
  const int beg = blockIdx.x * chunk;
  const int end = min(n, beg + chunk);
  int local = 0;
  for (int i = beg + threadIdx.x; i < end; i += 256) local += cnt[i];
  red[threadIdx.x] = local;
  __syncthreads();
#pragma unroll
  for (int off = 128; off > 0; off >>= 1) {
    if (threadIdx.x < off) red[threadIdx.x] += red[threadIdx.x + off];
    __syncthreads();
  }
  if (threadIdx.x == 0) blk_sum[blockIdx.x] = red[0];
}

// Pass 2b: single-block exclusive scan of SCAN_BLOCKS block sums (in-place).
__global__ __launch_bounds__(SCAN_BLOCKS) void scan_blk_k(int* __restrict__ blk_sum) {
  __shared__ int s[SCAN_BLOCKS];
  const int t = threadIdx.x;
  int v = blk_sum[t];
  s[t] = v;
  __syncthreads();
#pragma unroll
  for (int off = 1; off < SCAN_BLOCKS; off <<= 1) {
    int u = (t >= off) ? s[t - off] : 0;
    __syncthreads();
    s[t] += u;
    __syncthreads();
  }
  blk_sum[t] = s[t] - v;  // exclusive
}

// Pass 2c: per-block exclusive scan of its chunk, seeded by blk_sum.
//   cursor: counts in, exclusive prefix out.  row_off: stable copy.
__global__ __launch_bounds__(256) void scan_final_k(int* __restrict__ cursor,
                                                    int* __restrict__ row_off,
                                                    const int* __restrict__ blk_sum, int n) {
  __shared__ int s[256];
  const int chunk = (n + SCAN_BLOCKS - 1) / SCAN_BLOCKS;
  const int beg = blockIdx.x * chunk;
  const int end = min(n, beg + chunk);
  const int sub = (chunk + 255) / 256;
  const int tbeg = beg + threadIdx.x * sub;
  const int tend = min(end, tbeg + sub);
  int local = 0;
  for (int i = tbeg; i < tend; ++i) local += cursor[i];
  s[threadIdx.x] = local;
  __syncthreads();
#pragma unroll
  for (int off = 1; off < 256; off <<= 1) {
    int u = (threadIdx.x >= off) ? s[threadIdx.x - off] : 0;
    __syncthreads();
    s[threadIdx.x] += u;
    __syncthreads();
  }
  int running = blk_sum[blockIdx.x] + s[threadIdx.x] - local;
  for (int i = tbeg; i < tend; ++i) {
    int d = cursor[i];
    row_off[i] = running;
    cursor[i] = running;
    running += d;
  }
}

// ---------------------------------------------------------------------------
// Pass 3: fill CSR arrays, fusing sigmoid(edge_weight).
__global__ __launch_bounds__(256) void fill_k(const int* __restrict__ ei,
                                              const float* __restrict__ w,
                                              int* __restrict__ cursor,
                                              int* __restrict__ src_s,
                                              float* __restrict__ ew_s, int E) {
  int e = blockIdx.x * 256 + threadIdx.x;
  if (e >= E) return;
  int dst = ei[E + e];
  int pos = atomicAdd(&cursor[dst], 1);
  src_s[pos] = ei[e];
  ew_s[pos] = 1.0f / (1.0f + expf(-w[e]));
}

// ---------------------------------------------------------------------------
// Aggregation as gather: 32 lanes per destination node, one float4 chunk each.
__global__ __launch_bounds__(256) void gather_k(
    const float* __restrict__ feat, const int* __restrict__ row_off,
    const int* __restrict__ row_end, const int* __restrict__ src_s,
    const float* __restrict__ ew_s, float* __restrict__ aggr) {
  int gid = blockIdx.x * 256 + threadIdx.x;
  int node = gid >> 5;
  int c = gid & 31;
  if (node >= NN) return;
  int beg = row_off[node];
  int end = row_end[node];
  float4 acc = make_float4(0.f, 0.f, 0.f, 0.f);
  for (int e = beg; e < end; ++e) {
    int s = src_s[e];
    float wgt = ew_s[e];
    float4 v = *reinterpret_cast<const float4*>(feat + (size_t)s * DD + c * 4);
    acc.x = fmaf(v.x, wgt, acc.x);
    acc.y = fmaf(v.y, wgt, acc.y);
    acc.z = fmaf(v.z, wgt, acc.z);
    acc.w = fmaf(v.w, wgt, acc.w);
  }
  *reinterpret_cast<float4*>(aggr + (size_t)node * DD + c * 4) = acc;
}

// ---------------------------------------------------------------------------
// Fused dual-GEMM epilogue:  C = (relu?)( A1@W1 + A2@W2 + bias )
template <int HO, bool RELU>
__global__ __launch_bounds__(256) void gemm_fused_k(
    const float* __restrict__ A1, const float* __restrict__ A2,
    const float* __restrict__ W1, const float* __restrict__ W2,
    const float* __restrict__ bias, float* __restrict__ C, int n_rows) {
  constexpr int BN = 64;
  constexpr int K = 128;
  constexpr int BK = 32;
  constexpr int OG = HO / 4;
  constexpr int NG = 256 / OG;
  constexpr int NPG = BN / NG;

  __shared__ float A1s[BN][BK];
  __shared__ float A2s[BN][BK];
  __shared__ float W1s[BK][HO];
  __shared__ float W2s[BK][HO];

  const int t = threadIdx.x;
  const int og = t % OG;
  const int ng = t / OG;
  const int row0 = blockIdx.x * BN;

  float4 acc[NPG];
#pragma unroll
  for (int i = 0; i < NPG; ++i) acc[i] = make_float4(0.f, 0.f, 0.f, 0.f);

  for (int k0 = 0; k0 < K; k0 += BK) {
#pragma unroll
    for (int i = t; i < BN * BK / 4; i += 256) {
      int n = i / (BK / 4);
      int kq = i % (BK / 4);
      int gr = row0 + n;
      float4 a1 = make_float4(0.f, 0.f, 0.f, 0.f);
      float4 a2 = make_float4(0.f, 0.f, 0.f, 0.f);
      if (gr < n_rows) {
        a1 = *reinterpret_cast<const float4*>(&A1[(size_t)gr * K + k0 + kq * 4]);
        a2 = *reinterpret_cast<const float4*>(&A2[(size_t)gr * K + k0 + kq * 4]);
      }
      *reinterpret_cast<float4*>(&A1s[n][kq * 4]) = a1;
      *reinterpret_cast<float4*>(&A2s[n][kq * 4]) = a2;
    }
#pragma unroll
    for (int i = t; i < BK * HO / 4; i += 256) {
      int kk = i / (HO / 4);
      int hq = i % (HO / 4);
      *reinterpret_cast<float4*>(&W1s[kk][hq * 4]) =
          *reinterpret_cast<const float4*>(&W1[(size_t)(k0 + kk) * HO + hq * 4]);
      *reinterpret_cast<float4*>(&W2s[kk][hq * 4]) =
          *reinterpret_cast<const float4*>(&W2[(size_t)(k0 + kk) * HO + hq * 4]);
    }
    __syncthreads();

#pragma unroll
    for (int kk = 0; kk < BK; ++kk) {
      float4 w1 = *reinterpret_cast<const float4*>(&W1s[kk][og * 4]);
      float4 w2 = *reinterpret_cast<const float4*>(&W2s[kk][og * 4]);
#pragma unroll
      for (int i = 0; i < NPG; ++i) {
        float a1 = A1s[ng * NPG + i][kk];
        float a2 = A2s[ng * NPG + i][kk];
        acc[i].x = fmaf(a1, w1.x, acc[i].x);
        acc[i].y = fmaf(a1, w1.y, acc[i].y);
        acc[i].z = fmaf(a1, w1.z, acc[i].z);
        acc[i].w = fmaf(a1, w1.w, acc[i].w);
        acc[i].x = fmaf(a2, w2.x, acc[i].x);
        acc[i].y = fmaf(a2, w2.y, acc[i].y);
        acc[i].z = fmaf(a2, w2.z, acc[i].z);
        acc[i].w = fmaf(a2, w2.w, acc[i].w);
      }
    }
    __syncthreads();
  }

  const float4 b4 = *reinterpret_cast<const float4*>(&bias[og * 4]);
#pragma unroll
  for (int i = 0; i < NPG; ++i) {
    int gr = row0 + ng * NPG + i;
    if (gr < n_rows) {
      float4 o;
      o.x = acc[i].x + b4.x;
      o.y = acc[i].y + b4.y;
      o.z = acc[i].z + b4.z;
      o.w = acc[i].w + b4.w;
      if (RELU) {
        o.x = fmaxf(o.x, 0.f);
        o.y = fmaxf(o.y, 0.f);
        o.z = fmaxf(o.z, 0.f);
        o.w = fmaxf(o.w, 0.f);
      }
      *reinterpret_cast<float4*>(&C[(size_t)gr * HO + og * 4]) = o;
    }
  }
}

// ---------------------------------------------------------------------------
extern "C" void kernel_launch(void* const* d_in, const int* in_sizes, int n_in,
                              void* d_out, int out_size, void* d_ws, size_t ws_size,
                              hipStream_t stream) {
  const float* x   = (const float*)d_in[0];
  const float* w   = (const float*)d_in[1];
  const int*   ei  = (const int*)d_in[2];   // [2, E]: row0=src, row1=dst
  const float* Wr1 = (const float*)d_in[3];
  const float* br1 = (const float*)d_in[4];
  const float* Wo1 = (const float*)d_in[5];
  const float* Wr2 = (const float*)d_in[6];
  const float* br2 = (const float*)d_in[7];
  const float* Wo2 = (const float*)d_in[8];
  float* out = (float*)d_out;

  // Workspace layout (bytes):
  char* ws = (char*)d_ws;
  int*   row_off = (int*)(ws);                       // N ints      (400 KB)
  int*   cursor  = (int*)(ws + 400000);              // N ints      (400 KB)
  int*   blk_sum = (int*)(ws + 800000);              // 256 ints
  int*   src_s   = (int*)(ws + 801024);              // E ints      (6.4 MB)
  float* ew_s    = (float*)(ws + 7201024);           // E floats    (6.4 MB)
  float* aggr    = (float*)(ws + 13601024);          // N*128 f32   (51.2 MB)
  float* h       = (float*)(ws + 64801024);          // N*128 f32   (51.2 MB)
  // total: 116.0 MB

  const int egrid = (EE + 255) / 256;

  // ---- Build CSR (grouped by dst), fused sigmoid ----
  hipMemsetAsync(cursor, 0, (size_t)NN * sizeof(int), stream);
  count_k<<<egrid, 256, 0, stream>>>(ei, cursor, EE);
  scan_partial_k<<<SCAN_BLOCKS, 256, 0, stream>>>(cursor, blk_sum, NN);
  scan_blk_k<<<1, SCAN_BLOCKS, 0, stream>>>(blk_sum);
  scan_final_k<<<SCAN_BLOCKS, 256, 0, stream>>>(cursor, row_off, blk_sum, NN);
  fill_k<<<egrid, 256, 0, stream>>>(ei, w, cursor, src_s, ew_s, EE);
  // after fill: cursor[n] == row_off[n+1]  (row end)

  const int ggrid = (NN * 32 + 255) / 256;

  // ---- Layer 1 ----
  gather_k<<<ggrid, 256, 0, stream>>>(x, row_off, cursor, src_s, ew_s, aggr);
  gemm_fused_k<HH, true><<<(NN + 63) / 64, 256, 0, stream>>>(aggr, x, Wr1, Wo1, br1, h, NN);

  // ---- Layer 2 ----
  gather_k<<<ggrid, 256, 0, stream>>>(h, row_off, cursor, src_s, ew_s, aggr);
  gemm_fused_k<OO, false><<<(NN + 63) / 64, 256, 0, stream>>>(aggr, h, Wr2, Wo2, br2, out, NN);
}

// Round 4
// 382.941 us; speedup vs baseline: 14.5132x; 1.6134x over previous
//
#include <hip/hip_runtime.h>

// Problem constants (from reference)
#define NN 100000
#define EE 1600000
#define DD 128   // input dim
#define HH 128   // hidden dim
#define OO 64    // output dim

#define SCAN_BLOCKS 256

typedef unsigned short u16;
typedef __attribute__((ext_vector_type(8))) short bf16x8;  // 8 bf16 = 4 VGPR
typedef __attribute__((ext_vector_type(4))) float f32x4;

// ---------------------------------------------------------------------------
// bf16 helpers (RNE round, finite values only)
__device__ __forceinline__ u16 f2b(float f) {
  union { float f; unsigned u; } v; v.f = f;
  unsigned r = v.u + 0x7fffu + ((v.u >> 16) & 1u);
  return (u16)(r >> 16);
}
__device__ __forceinline__ float b2f(unsigned h) {
  union { unsigned u; float f; } v; v.u = h << 16;
  return v.f;
}

// ---------------------------------------------------------------------------
// Convert x [N,128] fp32 -> bf16 (8 elems per thread)
__global__ __launch_bounds__(256) void cvt_x_k(const float* __restrict__ x,
                                               u16* __restrict__ xb) {
  int i = blockIdx.x * 256 + threadIdx.x;  // chunk of 8 elems
  if (i >= NN * DD / 8) return;
  const float4* p = reinterpret_cast<const float4*>(x) + (size_t)i * 2;
  float4 a = p[0], b = p[1];
  uint4 o;
  o.x = (unsigned)f2b(a.x) | ((unsigned)f2b(a.y) << 16);
  o.y = (unsigned)f2b(a.z) | ((unsigned)f2b(a.w) << 16);
  o.z = (unsigned)f2b(b.x) | ((unsigned)f2b(b.y) << 16);
  o.w = (unsigned)f2b(b.z) | ((unsigned)f2b(b.w) << 16);
  reinterpret_cast<uint4*>(xb)[i] = o;
}

// ---------------------------------------------------------------------------
// Build stacked, transposed bf16 weights:
//   Wt1[n][k] (n<128, k<256) = k<128 ? Wrel1[k][n] : Wroot1[k-128][n]
//   Wt2[n][k] (n<64,  k<256) = k<128 ? Wrel2[k][n] : Wroot2[k-128][n]
__global__ __launch_bounds__(256) void cvt_w_k(
    const float* __restrict__ Wr1, const float* __restrict__ Wo1,
    const float* __restrict__ Wr2, const float* __restrict__ Wo2,
    u16* __restrict__ Wt1, u16* __restrict__ Wt2) {
  int i = blockIdx.x * 256 + threadIdx.x;
  if (i < 128 * 256) {
    int n = i >> 8, k = i & 255;
    float v = (k < 128) ? Wr1[k * 128 + n] : Wo1[(k - 128) * 128 + n];
    Wt1[i] = f2b(v);
  } else if (i < 128 * 256 + 64 * 256) {
    int j = i - 128 * 256;
    int n = j >> 8, k = j & 255;
    float v = (k < 128) ? Wr2[k * 64 + n] : Wo2[(k - 128) * 64 + n];
    Wt2[j] = f2b(v);
  }
}

// ---------------------------------------------------------------------------
// Pass 1: count in-degree per destination node (into cursor[])
__global__ __launch_bounds__(256) void count_k(const int* __restrict__ ei,
                                               int* __restrict__ cnt, int E) {
  int e = blockIdx.x * 256 + threadIdx.x;
  if (e < E) atomicAdd(&cnt[ei[E + e]], 1);
}

// Pass 2a: per-block partial sums of cnt[] chunks.
__global__ __launch_bounds__(256) void scan_partial_k(const int* __restrict__ cnt,
                                                      int* __restrict__ blk_sum, int n) {
  __shared__ int red[256];
  const int chunk = (n + SCAN_BLOCKS - 1) / SCAN_BLOCKS;
  const int beg = blockIdx.x * chunk;
  const int end = min(n, beg + chunk);
  int local = 0;
  for (int i = beg + threadIdx.x; i < end; i += 256) local += cnt[i];
  red[threadIdx.x] = local;
  __syncthreads();
#pragma unroll
  for (int off = 128; off > 0; off >>= 1) {
    if (threadIdx.x < off) red[threadIdx.x] += red[threadIdx.x + off];
    __syncthreads();
  }
  if (threadIdx.x == 0) blk_sum[blockIdx.x] = red[0];
}

// Pass 2b: single-block exclusive scan of SCAN_BLOCKS block sums (in-place).
__global__ __launch_bounds__(SCAN_BLOCKS) void scan_blk_k(int* __restrict__ blk_sum) {
  __shared__ int s[SCAN_BLOCKS];
  const int t = threadIdx.x;
  int v = blk_sum[t];
  s[t] = v;
  __syncthreads();
#pragma unroll
  for (int off = 1; off < SCAN_BLOCKS; off <<= 1) {
    int u = (t >= off) ? s[t - off] : 0;
    __syncthreads();
    s[t] += u;
    __syncthreads();
  }
  blk_sum[t] = s[t] - v;  // exclusive
}

// Pass 2c: per-block exclusive scan of its chunk, seeded by blk_sum.
__global__ __launch_bounds__(256) void scan_final_k(int* __restrict__ cursor,
                                                    int* __restrict__ row_off,
                                                    const int* __restrict__ blk_sum, int n) {
  __shared__ int s[256];
  const int chunk = (n + SCAN_BLOCKS - 1) / SCAN_BLOCKS;
  const int beg = blockIdx.x * chunk;
  const int end = min(n, beg + chunk);
  const int sub = (chunk + 255) / 256;
  const int tbeg = beg + threadIdx.x * sub;
  const int tend = min(end, tbeg + sub);
  int local = 0;
  for (int i = tbeg; i < tend; ++i) local += cursor[i];
  s[threadIdx.x] = local;
  __syncthreads();
#pragma unroll
  for (int off = 1; off < 256; off <<= 1) {
    int u = (threadIdx.x >= off) ? s[threadIdx.x - off] : 0;
    __syncthreads();
    s[threadIdx.x] += u;
    __syncthreads();
  }
  int running = blk_sum[blockIdx.x] + s[threadIdx.x] - local;
  for (int i = tbeg; i < tend; ++i) {
    int d = cursor[i];
    row_off[i] = running;
    cursor[i] = running;
    running += d;
  }
}

// ---------------------------------------------------------------------------
// Pass 3: fill CSR arrays, fusing sigmoid(edge_weight).
__global__ __launch_bounds__(256) void fill_k(const int* __restrict__ ei,
                                              const float* __restrict__ w,
                                              int* __restrict__ cursor,
                                              int* __restrict__ src_s,
                                              float* __restrict__ ew_s, int E) {
  int e = blockIdx.x * 256 + threadIdx.x;
  if (e >= E) return;
  int dst = ei[E + e];
  int pos = atomicAdd(&cursor[dst], 1);
  src_s[pos] = ei[e];
  ew_s[pos] = 1.0f / (1.0f + expf(-w[e]));
}

// ---------------------------------------------------------------------------
// Aggregation as gather over bf16 features: 16 lanes per node, 8 bf16 each.
// fp32 accumulate, bf16 output.
__global__ __launch_bounds__(256) void gather_k(
    const u16* __restrict__ feat, const int* __restrict__ row_off,
    const int* __restrict__ row_end, const int* __restrict__ src_s,
    const float* __restrict__ ew_s, u16* __restrict__ aggr) {
  int gid = blockIdx.x * 256 + threadIdx.x;
  int node = gid >> 4;
  int c = gid & 15;  // 8-elem chunk
  if (node >= NN) return;
  int beg = row_off[node];
  int end = row_end[node];
  float acc[8] = {0.f, 0.f, 0.f, 0.f, 0.f, 0.f, 0.f, 0.f};
  for (int e = beg; e < end; ++e) {
    int s = src_s[e];
    float w = ew_s[e];
    uint4 v = *reinterpret_cast<const uint4*>(feat + (size_t)s * DD + c * 8);
    acc[0] = fmaf(b2f(v.x & 0xffffu), w, acc[0]);
    acc[1] = fmaf(b2f(v.x >> 16), w, acc[1]);
    acc[2] = fmaf(b2f(v.y & 0xffffu), w, acc[2]);
    acc[3] = fmaf(b2f(v.y >> 16), w, acc[3]);
    acc[4] = fmaf(b2f(v.z & 0xffffu), w, acc[4]);
    acc[5] = fmaf(b2f(v.z >> 16), w, acc[5]);
    acc[6] = fmaf(b2f(v.w & 0xffffu), w, acc[6]);
    acc[7] = fmaf(b2f(v.w >> 16), w, acc[7]);
  }
  uint4 o;
  o.x = (unsigned)f2b(acc[0]) | ((unsigned)f2b(acc[1]) << 16);
  o.y = (unsigned)f2b(acc[2]) | ((unsigned)f2b(acc[3]) << 16);
  o.z = (unsigned)f2b(acc[4]) | ((unsigned)f2b(acc[5]) << 16);
  o.w = (unsigned)f2b(acc[6]) | ((unsigned)f2b(acc[7]) << 16);
  *reinterpret_cast<uint4*>(aggr + (size_t)node * DD + c * 8) = o;
}

// ---------------------------------------------------------------------------
// MFMA dual-GEMM:  C = (relu?)( [A1 | A2] @ Bt^T + bias )
//   A1,A2: [n_rows,128] bf16.  Bt: [HO][256] bf16 (stacked, transposed weights).
//   Block: 256 thr = 4 waves; tile 64 rows x HO cols; K=256 in steps of 32.
//   Wave w owns rows [w*16, w*16+16), all HO cols (CG = HO/16 accum frags).
template <int HO, bool RELU, bool OUTBF16>
__global__ __launch_bounds__(256) void gemm_mfma_k(
    const u16* __restrict__ A1, const u16* __restrict__ A2,
    const u16* __restrict__ Bt, const float* __restrict__ bias,
    void* __restrict__ Cout, int n_rows) {
  constexpr int CG = HO / 16;
  // 40-elem row stride: 80B, 16B-aligned, 2-way LDS bank aliasing only (free)
  __shared__ u16 As[64][40];
  __shared__ u16 Bs[HO][40];

  const int t = threadIdx.x;
  const int w = t >> 6;
  const int lane = t & 63;
  const int row0 = blockIdx.x * 64;

  f32x4 acc[CG];
#pragma unroll
  for (int cg = 0; cg < CG; ++cg) acc[cg] = (f32x4){0.f, 0.f, 0.f, 0.f};

  const int arow = w * 16 + (lane & 15);
  const int kq = (lane >> 4) * 8;

  for (int k0 = 0; k0 < 256; k0 += 32) {
    // stage A tile (64 x 32 bf16): one 16B chunk per thread
    {
      int node = t >> 2;
      int koff = (t & 3) * 8;
      int k = k0 + koff;
      int gr = row0 + node;
      uint4 v = make_uint4(0u, 0u, 0u, 0u);
      if (gr < n_rows) {
        const u16* src = (k < 128) ? (A1 + (size_t)gr * 128 + k)
                                   : (A2 + (size_t)gr * 128 + (k - 128));
        v = *reinterpret_cast<const uint4*>(src);
      }
      *reinterpret_cast<uint4*>(&As[node][koff]) = v;
    }
    // stage B tile (HO x 32 bf16)
#pragma unroll
    for (int i = 0; i < CG / 4; ++i) {
      int c2 = t + i * 256;        // chunk id < HO*4
      int n = c2 >> 2;
      int koff = (c2 & 3) * 8;
      uint4 v = *reinterpret_cast<const uint4*>(Bt + (size_t)n * 256 + k0 + koff);
      *reinterpret_cast<uint4*>(&Bs[n][koff]) = v;
    }
    __syncthreads();

    bf16x8 a = *reinterpret_cast<const bf16x8*>(&As[arow][kq]);
#pragma unroll
    for (int cg = 0; cg < CG; ++cg) {
      bf16x8 b = *reinterpret_cast<const bf16x8*>(&Bs[cg * 16 + (lane & 15)][kq]);
      acc[cg] = __builtin_amdgcn_mfma_f32_16x16x32_bf16(a, b, acc[cg], 0, 0, 0);
    }
    __syncthreads();
  }

  // epilogue: C row = (lane>>4)*4 + j (within wave's 16), col = cg*16 + (lane&15)
  const int rbase = w * 16 + ((lane >> 4) << 2);
#pragma unroll
  for (int cg = 0; cg < CG; ++cg) {
    int col = cg * 16 + (lane & 15);
    float bia = bias[col];
#pragma unroll
    for (int j = 0; j < 4; ++j) {
      int gr = row0 + rbase + j;
      if (gr < n_rows) {
        float v = acc[cg][j] + bia;
        if (RELU) v = fmaxf(v, 0.f);
        if (OUTBF16) ((u16*)Cout)[(size_t)gr * HO + col] = f2b(v);
        else ((float*)Cout)[(size_t)gr * HO + col] = v;
      }
    }
  }
}

// ---------------------------------------------------------------------------
extern "C" void kernel_launch(void* const* d_in, const int* in_sizes, int n_in,
                              void* d_out, int out_size, void* d_ws, size_t ws_size,
                              hipStream_t stream) {
  const float* x   = (const float*)d_in[0];
  const float* w   = (const float*)d_in[1];
  const int*   ei  = (const int*)d_in[2];   // [2, E]: row0=src, row1=dst
  const float* Wr1 = (const float*)d_in[3];
  const float* br1 = (const float*)d_in[4];
  const float* Wo1 = (const float*)d_in[5];
  const float* Wr2 = (const float*)d_in[6];
  const float* br2 = (const float*)d_in[7];
  const float* Wo2 = (const float*)d_in[8];
  float* out = (float*)d_out;

  // Workspace layout (bytes, all offsets 16B-aligned):
  char* ws = (char*)d_ws;
  int*   row_off = (int*)(ws);                        // N ints        400,000
  int*   cursor  = (int*)(ws + 400000);               // N ints        400,000
  int*   blk_sum = (int*)(ws + 800000);               // 256 ints        1,024
  int*   src_s   = (int*)(ws + 801024);               // E ints      6,400,000
  float* ew_s    = (float*)(ws + 7201024);            // E floats    6,400,000
  u16*   xb      = (u16*)(ws + 13601024);             // N*128 bf16 25,600,000
  u16*   hb      = (u16*)(ws + 39201024);             // N*128 bf16 25,600,000
  u16*   aggrb   = (u16*)(ws + 64801024);             // N*128 bf16 25,600,000
  u16*   Wt1     = (u16*)(ws + 90401024);             // 128*256 bf16   65,536
  u16*   Wt2     = (u16*)(ws + 90466560);             // 64*256 bf16    32,768
  // total ~90.5 MB

  const int egrid = (EE + 255) / 256;

  // ---- Prep: bf16 conversions ----
  cvt_x_k<<<NN * DD / 8 / 256, 256, 0, stream>>>(x, xb);
  cvt_w_k<<<(192 * 256 + 255) / 256, 256, 0, stream>>>(Wr1, Wo1, Wr2, Wo2, Wt1, Wt2);

  // ---- Build CSR (grouped by dst), fused sigmoid ----
  hipMemsetAsync(cursor, 0, (size_t)NN * sizeof(int), stream);
  count_k<<<egrid, 256, 0, stream>>>(ei, cursor, EE);
  scan_partial_k<<<SCAN_BLOCKS, 256, 0, stream>>>(cursor, blk_sum, NN);
  scan_blk_k<<<1, SCAN_BLOCKS, 0, stream>>>(blk_sum);
  scan_final_k<<<SCAN_BLOCKS, 256, 0, stream>>>(cursor, row_off, blk_sum, NN);
  fill_k<<<egrid, 256, 0, stream>>>(ei, w, cursor, src_s, ew_s, EE);
  // after fill: cursor[n] == row_off[n+1]  (row end)

  const int ggrid = (NN * 16 + 255) / 256;
  const int mgrid = (NN + 63) / 64;

  // ---- Layer 1 ----
  gather_k<<<ggrid, 256, 0, stream>>>(xb, row_off, cursor, src_s, ew_s, aggrb);
  gemm_mfma_k<HH, true, true><<<mgrid, 256, 0, stream>>>(aggrb, xb, Wt1, br1, hb, NN);

  // ---- Layer 2 ----
  gather_k<<<ggrid, 256, 0, stream>>>(hb, row_off, cursor, src_s, ew_s, aggrb);
  gemm_mfma_k<OO, false, false><<<mgrid, 256, 0, stream>>>(aggrb, hb, Wt2, br2, out, NN);
}

// Round 5
// 373.156 us; speedup vs baseline: 14.8938x; 1.0262x over previous
//
#include <hip/hip_runtime.h>

// Problem constants (from reference)
#define NN 100000
#define EE 1600000
#define DD 128   // input dim
#define HH 128   // hidden dim
#define OO 64    // output dim

#define SCAN_BLOCKS 256
#define NPART 4          // dst-range partitions for CSR fill (write locality)

typedef unsigned short u16;
typedef __attribute__((ext_vector_type(8))) short bf16x8;  // 8 bf16 = 4 VGPR
typedef __attribute__((ext_vector_type(4))) float f32x4;

// ---------------------------------------------------------------------------
// bf16 helpers (RNE round, finite values only)
__device__ __forceinline__ u16 f2b(float f) {
  union { float f; unsigned u; } v; v.f = f;
  unsigned r = v.u + 0x7fffu + ((v.u >> 16) & 1u);
  return (u16)(r >> 16);
}
__device__ __forceinline__ float b2f(unsigned h) {
  union { unsigned u; float f; } v; v.u = h << 16;
  return v.f;
}

// ---------------------------------------------------------------------------
// Convert x [N,128] fp32 -> bf16 (8 elems per thread)
__global__ __launch_bounds__(256) void cvt_x_k(const float* __restrict__ x,
                                               u16* __restrict__ xb) {
  int i = blockIdx.x * 256 + threadIdx.x;  // chunk of 8 elems
  if (i >= NN * DD / 8) return;
  const float4* p = reinterpret_cast<const float4*>(x) + (size_t)i * 2;
  float4 a = p[0], b = p[1];
  uint4 o;
  o.x = (unsigned)f2b(a.x) | ((unsigned)f2b(a.y) << 16);
  o.y = (unsigned)f2b(a.z) | ((unsigned)f2b(a.w) << 16);
  o.z = (unsigned)f2b(b.x) | ((unsigned)f2b(b.y) << 16);
  o.w = (unsigned)f2b(b.z) | ((unsigned)f2b(b.w) << 16);
  reinterpret_cast<uint4*>(xb)[i] = o;
}

// ---------------------------------------------------------------------------
// Build stacked, transposed bf16 weights:
//   Wt1[n][k] (n<128, k<256) = k<128 ? Wrel1[k][n] : Wroot1[k-128][n]
//   Wt2[n][k] (n<64,  k<256) = k<128 ? Wrel2[k][n] : Wroot2[k-128][n]
__global__ __launch_bounds__(256) void cvt_w_k(
    const float* __restrict__ Wr1, const float* __restrict__ Wo1,
    const float* __restrict__ Wr2, const float* __restrict__ Wo2,
    u16* __restrict__ Wt1, u16* __restrict__ Wt2) {
  int i = blockIdx.x * 256 + threadIdx.x;
  if (i < 128 * 256) {
    int n = i >> 8, k = i & 255;
    float v = (k < 128) ? Wr1[k * 128 + n] : Wo1[(k - 128) * 128 + n];
    Wt1[i] = f2b(v);
  } else if (i < 128 * 256 + 64 * 256) {
    int j = i - 128 * 256;
    int n = j >> 8, k = j & 255;
    float v = (k < 128) ? Wr2[k * 64 + n] : Wo2[(k - 128) * 64 + n];
    Wt2[j] = f2b(v);
  }
}

// ---------------------------------------------------------------------------
// Pass 1: count in-degree per destination node (into cursor[])
__global__ __launch_bounds__(256) void count_k(const int* __restrict__ ei,
                                               int* __restrict__ cnt, int E) {
  int e = blockIdx.x * 256 + threadIdx.x;
  if (e < E) atomicAdd(&cnt[ei[E + e]], 1);
}

// Pass 2a: per-block partial sums of cnt[] chunks.
__global__ __launch_bounds__(256) void scan_partial_k(const int* __restrict__ cnt,
                                                      int* __restrict__ blk_sum, int n) {
  __shared__ int red[256];
  const int chunk = (n + SCAN_BLOCKS - 1) / SCAN_BLOCKS;
  const int beg = blockIdx.x * chunk;
  const int end = min(n, beg + chunk);
  int local = 0;
  for (int i = beg + threadIdx.x; i < end; i += 256) local += cnt[i];
  red[threadIdx.x] = local;
  __syncthreads();
#pragma unroll
  for (int off = 128; off > 0; off >>= 1) {
    if (threadIdx.x < off) red[threadIdx.x] += red[threadIdx.x + off];
    __syncthreads();
  }
  if (threadIdx.x == 0) blk_sum[blockIdx.x] = red[0];
}

// Pass 2b: single-block exclusive scan of SCAN_BLOCKS block sums (in-place).
__global__ __launch_bounds__(SCAN_BLOCKS) void scan_blk_k(int* __restrict__ blk_sum) {
  __shared__ int s[SCAN_BLOCKS];
  const int t = threadIdx.x;
  int v = blk_sum[t];
  s[t] = v;
  __syncthreads();
#pragma unroll
  for (int off = 1; off < SCAN_BLOCKS; off <<= 1) {
    int u = (t >= off) ? s[t - off] : 0;
    __syncthreads();
    s[t] += u;
    __syncthreads();
  }
  blk_sum[t] = s[t] - v;  // exclusive
}

// Pass 2c: per-block exclusive scan of its chunk, seeded by blk_sum.
__global__ __launch_bounds__(256) void scan_final_k(int* __restrict__ cursor,
                                                    int* __restrict__ row_off,
                                                    const int* __restrict__ blk_sum, int n) {
  __shared__ int s[256];
  const int chunk = (n + SCAN_BLOCKS - 1) / SCAN_BLOCKS;
  const int beg = blockIdx.x * chunk;
  const int end = min(n, beg + chunk);
  const int sub = (chunk + 255) / 256;
  const int tbeg = beg + threadIdx.x * sub;
  const int tend = min(end, tbeg + sub);
  int local = 0;
  for (int i = tbeg; i < tend; ++i) local += cursor[i];
  s[threadIdx.x] = local;
  __syncthreads();
#pragma unroll
  for (int off = 1; off < 256; off <<= 1) {
    int u = (threadIdx.x >= off) ? s[threadIdx.x - off] : 0;
    __syncthreads();
    s[threadIdx.x] += u;
    __syncthreads();
  }
  int running = blk_sum[blockIdx.x] + s[threadIdx.x] - local;
  for (int i = tbeg; i < tend; ++i) {
    int d = cursor[i];
    row_off[i] = running;
    cursor[i] = running;
    running += d;
  }
}

// ---------------------------------------------------------------------------
// Pass 3 (partitioned): fill CSR records for dst in [lo, hi), fusing sigmoid.
// Record = uint2{ src, float_bits(sigmoid(w)) }.  Restricting dst-range keeps
// the scattered 8B writes inside a ~3.2MB slice -> L2-resident, full-line
// evictions (write traffic ~12.8MB total instead of 153MB).
__global__ __launch_bounds__(256) void fill_part_k(const int* __restrict__ ei,
                                                   const float* __restrict__ w,
                                                   int* __restrict__ cursor,
                                                   uint2* __restrict__ recs,
                                                   int lo, int hi, int E) {
  int e = blockIdx.x * 256 + threadIdx.x;
  if (e >= E) return;
  int dst = ei[E + e];
  if (dst < lo || dst >= hi) return;
  int pos = atomicAdd(&cursor[dst], 1);
  float sig = 1.0f / (1.0f + expf(-w[e]));
  recs[pos] = make_uint2((unsigned)ei[e], __float_as_uint(sig));
}

// ---------------------------------------------------------------------------
// Aggregation as gather over bf16 features: 16 lanes per node, 8 bf16 each.
// fp32 accumulate, bf16 output.
__global__ __launch_bounds__(256) void gather_k(
    const u16* __restrict__ feat, const int* __restrict__ row_off,
    const int* __restrict__ row_end, const uint2* __restrict__ recs,
    u16* __restrict__ aggr) {
  int gid = blockIdx.x * 256 + threadIdx.x;
  int node = gid >> 4;
  int c = gid & 15;  // 8-elem chunk
  if (node >= NN) return;
  int beg = row_off[node];
  int end = row_end[node];
  float acc[8] = {0.f, 0.f, 0.f, 0.f, 0.f, 0.f, 0.f, 0.f};
  for (int e = beg; e < end; ++e) {
    uint2 r = recs[e];
    float w = __uint_as_float(r.y);
    uint4 v = *reinterpret_cast<const uint4*>(feat + (size_t)r.x * DD + c * 8);
    acc[0] = fmaf(b2f(v.x & 0xffffu), w, acc[0]);
    acc[1] = fmaf(b2f(v.x >> 16), w, acc[1]);
    acc[2] = fmaf(b2f(v.y & 0xffffu), w, acc[2]);
    acc[3] = fmaf(b2f(v.y >> 16), w, acc[3]);
    acc[4] = fmaf(b2f(v.z & 0xffffu), w, acc[4]);
    acc[5] = fmaf(b2f(v.z >> 16), w, acc[5]);
    acc[6] = fmaf(b2f(v.w & 0xffffu), w, acc[6]);
    acc[7] = fmaf(b2f(v.w >> 16), w, acc[7]);
  }
  uint4 o;
  o.x = (unsigned)f2b(acc[0]) | ((unsigned)f2b(acc[1]) << 16);
  o.y = (unsigned)f2b(acc[2]) | ((unsigned)f2b(acc[3]) << 16);
  o.z = (unsigned)f2b(acc[4]) | ((unsigned)f2b(acc[5]) << 16);
  o.w = (unsigned)f2b(acc[6]) | ((unsigned)f2b(acc[7]) << 16);
  *reinterpret_cast<uint4*>(aggr + (size_t)node * DD + c * 8) = o;
}

// ---------------------------------------------------------------------------
// MFMA dual-GEMM:  C = (relu?)( [A1 | A2] @ Bt^T + bias )
//   A1,A2: [n_rows,128] bf16.  Bt: [HO][256] bf16 (stacked, transposed weights).
template <int HO, bool RELU, bool OUTBF16>
__global__ __launch_bounds__(256) void gemm_mfma_k(
    const u16* __restrict__ A1, const u16* __restrict__ A2,
    const u16* __restrict__ Bt, const float* __restrict__ bias,
    void* __restrict__ Cout, int n_rows) {
  constexpr int CG = HO / 16;
  __shared__ u16 As[64][40];
  __shared__ u16 Bs[HO][40];

  const int t = threadIdx.x;
  const int w = t >> 6;
  const int lane = t & 63;
  const int row0 = blockIdx.x * 64;

  f32x4 acc[CG];
#pragma unroll
  for (int cg = 0; cg < CG; ++cg) acc[cg] = (f32x4){0.f, 0.f, 0.f, 0.f};

  const int arow = w * 16 + (lane & 15);
  const int kq = (lane >> 4) * 8;

  for (int k0 = 0; k0 < 256; k0 += 32) {
    {
      int node = t >> 2;
      int koff = (t & 3) * 8;
      int k = k0 + koff;
      int gr = row0 + node;
      uint4 v = make_uint4(0u, 0u, 0u, 0u);
      if (gr < n_rows) {
        const u16* src = (k < 128) ? (A1 + (size_t)gr * 128 + k)
                                   : (A2 + (size_t)gr * 128 + (k - 128));
        v = *reinterpret_cast<const uint4*>(src);
      }
      *reinterpret_cast<uint4*>(&As[node][koff]) = v;
    }
#pragma unroll
    for (int i = 0; i < CG / 4; ++i) {
      int c2 = t + i * 256;
      int n = c2 >> 2;
      int koff = (c2 & 3) * 8;
      uint4 v = *reinterpret_cast<const uint4*>(Bt + (size_t)n * 256 + k0 + koff);
      *reinterpret_cast<uint4*>(&Bs[n][koff]) = v;
    }
    __syncthreads();

    bf16x8 a = *reinterpret_cast<const bf16x8*>(&As[arow][kq]);
#pragma unroll
    for (int cg = 0; cg < CG; ++cg) {
      bf16x8 b = *reinterpret_cast<const bf16x8*>(&Bs[cg * 16 + (lane & 15)][kq]);
      acc[cg] = __builtin_amdgcn_mfma_f32_16x16x32_bf16(a, b, acc[cg], 0, 0, 0);
    }
    __syncthreads();
  }

  const int rbase = w * 16 + ((lane >> 4) << 2);
#pragma unroll
  for (int cg = 0; cg < CG; ++cg) {
    int col = cg * 16 + (lane & 15);
    float bia = bias[col];
#pragma unroll
    for (int j = 0; j < 4; ++j) {
      int gr = row0 + rbase + j;
      if (gr < n_rows) {
        float v = acc[cg][j] + bia;
        if (RELU) v = fmaxf(v, 0.f);
        if (OUTBF16) ((u16*)Cout)[(size_t)gr * HO + col] = f2b(v);
        else ((float*)Cout)[(size_t)gr * HO + col] = v;
      }
    }
  }
}

// ---------------------------------------------------------------------------
extern "C" void kernel_launch(void* const* d_in, const int* in_sizes, int n_in,
                              void* d_out, int out_size, void* d_ws, size_t ws_size,
                              hipStream_t stream) {
  const float* x   = (const float*)d_in[0];
  const float* w   = (const float*)d_in[1];
  const int*   ei  = (const int*)d_in[2];   // [2, E]: row0=src, row1=dst
  const float* Wr1 = (const float*)d_in[3];
  const float* br1 = (const float*)d_in[4];
  const float* Wo1 = (const float*)d_in[5];
  const float* Wr2 = (const float*)d_in[6];
  const float* br2 = (const float*)d_in[7];
  const float* Wo2 = (const float*)d_in[8];
  float* out = (float*)d_out;

  // Workspace layout (bytes, all offsets 16B-aligned):
  char* ws = (char*)d_ws;
  int*   row_off = (int*)(ws);                        // N ints        400,000
  int*   cursor  = (int*)(ws + 400000);               // N ints        400,000
  int*   blk_sum = (int*)(ws + 800000);               // 256 ints        1,024
  uint2* recs    = (uint2*)(ws + 801024);             // E uint2    12,800,000
  u16*   xb      = (u16*)(ws + 13601024);             // N*128 bf16 25,600,000
  u16*   hb      = (u16*)(ws + 39201024);             // N*128 bf16 25,600,000
  u16*   aggrb   = (u16*)(ws + 64801024);             // N*128 bf16 25,600,000
  u16*   Wt1     = (u16*)(ws + 90401024);             // 128*256 bf16   65,536
  u16*   Wt2     = (u16*)(ws + 90466560);             // 64*256 bf16    32,768
  // total ~90.5 MB

  const int egrid = (EE + 255) / 256;

  // ---- Prep: bf16 conversions ----
  cvt_x_k<<<NN * DD / 8 / 256, 256, 0, stream>>>(x, xb);
  cvt_w_k<<<(192 * 256 + 255) / 256, 256, 0, stream>>>(Wr1, Wo1, Wr2, Wo2, Wt1, Wt2);

  // ---- Build CSR (grouped by dst), fused sigmoid ----
  hipMemsetAsync(cursor, 0, (size_t)NN * sizeof(int), stream);
  count_k<<<egrid, 256, 0, stream>>>(ei, cursor, EE);
  scan_partial_k<<<SCAN_BLOCKS, 256, 0, stream>>>(cursor, blk_sum, NN);
  scan_blk_k<<<1, SCAN_BLOCKS, 0, stream>>>(blk_sum);
  scan_final_k<<<SCAN_BLOCKS, 256, 0, stream>>>(cursor, row_off, blk_sum, NN);
  // Partitioned fill: each pass's writes land in a contiguous L2-resident slice.
  {
    const int pstep = (NN + NPART - 1) / NPART;
    for (int p = 0; p < NPART; ++p) {
      int lo = p * pstep;
      int hi = min(NN, lo + pstep);
      fill_part_k<<<egrid, 256, 0, stream>>>(ei, w, cursor, recs, lo, hi, EE);
    }
  }
  // after fill: cursor[n] == row_off[n+1]  (row end)

  const int ggrid = (NN * 16 + 255) / 256;
  const int mgrid = (NN + 63) / 64;

  // ---- Layer 1 ----
  gather_k<<<ggrid, 256, 0, stream>>>(xb, row_off, cursor, recs, aggrb);
  gemm_mfma_k<HH, true, true><<<mgrid, 256, 0, stream>>>(aggrb, xb, Wt1, br1, hb, NN);

  // ---- Layer 2 ----
  gather_k<<<ggrid, 256, 0, stream>>>(hb, row_off, cursor, recs, aggrb);
  gemm_mfma_k<OO, false, false><<<mgrid, 256, 0, stream>>>(aggrb, hb, Wt2, br2, out, NN);
}